// Round 4
// baseline (1095.902 us; speedup 1.0000x reference)
//
#include <hip/hip_runtime.h>

// RPDC depthwise sparse-5x5 (pixel-difference) conv.
// x: (16,256,128,128) fp32, weight: (256,1,3,3) fp32, out same shape.
//
// For output row o (taps tj = weight flat [1+j]):
//   + t0*x[o-2][w-2] + t1*x[o-2][w] + t2*x[o-2][w+2]          (A role)
//   - t0*x[o-1][w-1] - t1*x[o-1][w] - t2*x[o-1][w+1]          (B role)
//   + t3*(x[o][w-2]-x[o][w-1]) + t4*(x[o][w+2]-x[o][w+1])     (C role)
//   - t5*x[o+1][w-1] - t6*x[o+1][w] - t7*x[o+1][w+1]          (D role)
//   + t5*x[o+2][w-2] + t6*x[o+2][w] + t7*x[o+2][w+2]          (E role)
//
// v5: STREAMING ACCUMULATORS. v2/v4 kept a 6x8-row register ring (48 VGPR of
// state) -> ~110 VGPR -> 4 waves/SIMD -> latency-bound at ~143 us. Same
// FLOPs restructured: hold 5 rotating partial-output accumulators (20 VGPR);
// each arriving input row r scatters its A/B/C/D/E contributions into
// acc[(r-2..r+2)%5]; out row o completes (and stores) when row o+2 arrives.
// State ~60 VGPR -> __launch_bounds__(256,8) -> 8 waves/SIMD, exactly one
// resident generation (2048 blocks x 4 waves = 256 CU x 2048 threads).
// One float4 load per row; halo cols via ds_bpermute (edge lanes are the
// zero-pad lanes, masked by ml/mr). Depth-2 load pipeline, running pointers.

#define HH 128
#define WW 128
#define CHUNK 32               // rows per thread-strip
#define SPB 8                  // strips per 256-thread block

__device__ __forceinline__ float bperm(int addr, float v) {
    return __int_as_float(__builtin_amdgcn_ds_bpermute(addr, __float_as_int(v)));
}

__global__ __launch_bounds__(256, 8) void rpdc_kernel(
    const float* __restrict__ x, const float* __restrict__ wt,
    float* __restrict__ out, int C)
{
    const int tid   = threadIdx.x;
    const int l     = tid & 31;                      // col-group lane (4 cols)
    const int s     = blockIdx.x * SPB + (tid >> 5); // strip = (plane, chunk)
    const int plane = s >> 2;                        // n*C + c
    const int h0    = (s & 3) * CHUNK;
    const int c     = plane & (C - 1);               // C = 256 (pow2)

    const float* wp = wt + (size_t)c * 9;
    const float t0 = wp[1], t1 = wp[2], t2 = wp[3], t3 = wp[4];
    const float t4 = wp[5], t5 = wp[6], t6 = wp[7], t7 = wp[8];

    const int w0 = l * 4;                            // first owned column
    const float ml = (l == 0) ? 0.f : 1.f;           // zero-pad masks
    const float mr = (l == 31) ? 0.f : 1.f;

    // ds_bpermute byte addrs for lane +/- 1 (wave-wrap; edges masked)
    const int lane = tid & 63;
    const int upA  = ((lane - 1) & 63) * 4;
    const int dnA  = ((lane + 1) & 63) * 4;

    // running pointers (keep unrolled addressing in 2 VGPR pairs + adds)
    const float* pn = x + (size_t)plane * (HH * WW) + (size_t)(h0 - 2) * WW + w0;
    int rn = h0 - 2;                                 // absolute row of pn
    float* po = out + (size_t)plane * (HH * WW) + (size_t)h0 * WW + w0;

    float acc[5][4];                                 // acc[o%5] = partial out row o
    float4 s0, s1;                                   // staged rows (depth-2)

    auto issue = [&](float4& v) {
        if ((unsigned)rn < (unsigned)HH) {
            v = *(const float4*)pn;
        } else {
            v = make_float4(0.f, 0.f, 0.f, 0.f);     // zero pad
        }
        pn += WW; ++rn;
    };

    issue(s0);                                       // row rr = -2
    issue(s1);                                       // row rr = -1

#pragma unroll
    for (int i = 0; i < CHUNK + 4; ++i) {
        const int rr = i - 2;                        // arriving input row (rel)

        float4 nv;                                   // issue row rr+2
        if (i < CHUNK + 2) issue(nv);
        else nv = make_float4(0.f, 0.f, 0.f, 0.f);

        // extend arriving row (s0) to cols w0-2..w0+5
        float X[8];
        X[0] = bperm(upA, s0.z) * ml;                // col w0-2 (lane l-1 .z)
        X[1] = bperm(upA, s0.w) * ml;                // col w0-1
        X[2] = s0.x; X[3] = s0.y; X[4] = s0.z; X[5] = s0.w;
        X[6] = bperm(dnA, s0.x) * mr;                // col w0+4 (lane l+1 .x)
        X[7] = bperm(dnA, s0.y) * mr;                // col w0+5
        s0 = s1; s1 = nv;                            // renamed by full unroll

        // A role: INIT out row rr+2 (slot was stored+freed last iteration)
        if (rr + 2 < CHUNK) {                        // rr+2 >= 0 always
            float* a = acc[(rr + 2) % 5];
#pragma unroll
            for (int j = 0; j < 4; ++j)
                a[j] = t0 * X[j] + t1 * X[j + 2] + t2 * X[j + 4];
        }
        // B role: out row rr+1
        if (rr + 1 >= 0 && rr + 1 < CHUNK) {
            float* a = acc[(rr + 1) % 5];
#pragma unroll
            for (int j = 0; j < 4; ++j)
                a[j] -= t0 * X[j + 1] + t1 * X[j + 2] + t2 * X[j + 3];
        }
        // C role: out row rr
        if (rr >= 0 && rr < CHUNK) {
            float* a = acc[rr % 5];
#pragma unroll
            for (int j = 0; j < 4; ++j)
                a[j] += t3 * (X[j] - X[j + 1]) + t4 * (X[j + 4] - X[j + 3]);
        }
        // D role: out row rr-1
        if (rr - 1 >= 0 && rr - 1 < CHUNK) {
            float* a = acc[(rr - 1) % 5];
#pragma unroll
            for (int j = 0; j < 4; ++j)
                a[j] -= t5 * X[j + 1] + t6 * X[j + 2] + t7 * X[j + 3];
        }
        // E role: complete + store out row rr-2
        if (rr - 2 >= 0) {                           // rr-2 <= 31 always
            float* a = acc[(rr - 2) % 5];
#pragma unroll
            for (int j = 0; j < 4; ++j)
                a[j] += t5 * X[j] + t6 * X[j + 2] + t7 * X[j + 4];
            *(float4*)po = make_float4(a[0], a[1], a[2], a[3]);
            po += WW;
        }
    }
}

extern "C" void kernel_launch(void* const* d_in, const int* in_sizes, int n_in,
                              void* d_out, int out_size, void* d_ws, size_t ws_size,
                              hipStream_t stream) {
    const float* x = (const float*)d_in[0];
    const float* wt = (const float*)d_in[1];
    float* out = (float*)d_out;

    const int C = in_sizes[1] / 9;                 // 256
    const int planes = in_sizes[0] / (HH * WW);    // N*C = 4096

    // strips = planes * (HH/CHUNK); 8 strips (2 planes) per 256-thread block
    dim3 grid(planes * (HH / CHUNK) / SPB);        // 2048
    dim3 block(256);
    rpdc_kernel<<<grid, block, 0, stream>>>(x, wt, out, C);
}

// Round 5
// 1086.697 us; speedup vs baseline: 1.0085x; 1.0085x over previous
//
#include <hip/hip_runtime.h>

// RPDC depthwise sparse-5x5 (pixel-difference) conv.
// x: (16,256,128,128) fp32, weight: (256,1,3,3) fp32, out same shape.
//
// For output row o (taps tj = weight flat [1+j]):
//   A: + t0*x[o-2][w-2] + t1*x[o-2][w] + t2*x[o-2][w+2]
//   B: - t0*x[o-1][w-1] - t1*x[o-1][w] - t2*x[o-1][w+1]
//   C: + t3*(x[o][w-2]-x[o][w-1]) + t4*(x[o][w+2]-x[o][w+1])
//   D: - t5*x[o+1][w-1] - t6*x[o+1][w] - t7*x[o+1][w+1]
//   E: + t5*x[o+2][w-2] + t6*x[o+2][w] + t7*x[o+2][w+2]
//
// v6: v5's streaming-accumulator dataflow made scratch-proof. v5 spilled
// (VGPR=32, WRITE 268->1115 MB): the 36-iter loop didn't fully unroll, so
// acc[(rr+k)%5] became runtime-indexed -> scratch (rule: runtime-indexed
// arrays go to local memory). v6 uses ZERO arrays: five named float4 accs
// (q0..q4), eight named floats for the extended row, and the period-5
// rotation written out as 36 macro-expanded straight-line steps with literal
// register names. Taps hoisted to SGPRs via readfirstlane (wave = 2 strips
// of the SAME plane: even s and s+1 share s>>2). State ~55 VGPR ->
// __launch_bounds__(256,8) (cap 64) -> 8 waves/SIMD, one full resident
// generation (2048 blocks x 4 waves = 256 CU x 32 waves).
// One float4 load per row; halo cols via ds_bpermute (edge lanes are the
// zero-pad lanes, masked by ml/mr). Depth-2 load pipeline (load row rr+2
// while computing row rr).

#define HH 128
#define WW 128
#define CHUNK 32               // rows per thread-strip
#define SPB 8                  // strips per 256-thread block

__device__ __forceinline__ float bperm(int addr, float v) {
    return __int_as_float(__builtin_amdgcn_ds_bpermute(addr, __float_as_int(v)));
}
__device__ __forceinline__ float rfl(float v) {
    return __int_as_float(__builtin_amdgcn_readfirstlane(__float_as_int(v)));
}

// load next input row (zero outside plane), advance pointer
#define LOADROW(dst) { \
    if ((unsigned)rn < (unsigned)HH) dst = *(const float4*)pn; \
    else dst = make_float4(0.f, 0.f, 0.f, 0.f); \
    pn += WW; ++rn; }

// issue load for row rr+2 (optional), extend current row s0 -> x0..x7
// (cols w0-2..w0+5 via neighbor-lane bpermute), shift pipeline
#define EXT_SHIFT(DO_LOAD) { \
    float4 nv_; \
    if (DO_LOAD) { LOADROW(nv_) } \
    else nv_ = make_float4(0.f, 0.f, 0.f, 0.f); \
    x0 = bperm(upA, s0.z) * ml;  x1 = bperm(upA, s0.w) * ml; \
    x2 = s0.x; x3 = s0.y; x4 = s0.z; x5 = s0.w; \
    x6 = bperm(dnA, s0.x) * mr;  x7 = bperm(dnA, s0.y) * mr; \
    s0 = s1; s1 = nv_; }

#define ROLE_A(q) { \
    q.x = t0*x0 + t1*x2 + t2*x4;  q.y = t0*x1 + t1*x3 + t2*x5; \
    q.z = t0*x2 + t1*x4 + t2*x6;  q.w = t0*x3 + t1*x5 + t2*x7; }
#define ROLE_B(q) { \
    q.x -= t0*x1 + t1*x2 + t2*x3;  q.y -= t0*x2 + t1*x3 + t2*x4; \
    q.z -= t0*x3 + t1*x4 + t2*x5;  q.w -= t0*x4 + t1*x5 + t2*x6; }
#define ROLE_C(q) { \
    q.x += t3*(x0-x1) + t4*(x4-x3);  q.y += t3*(x1-x2) + t4*(x5-x4); \
    q.z += t3*(x2-x3) + t4*(x6-x5);  q.w += t3*(x3-x4) + t4*(x7-x6); }
#define ROLE_D(q) { \
    q.x -= t5*x1 + t6*x2 + t7*x3;  q.y -= t5*x2 + t6*x3 + t7*x4; \
    q.z -= t5*x3 + t6*x4 + t7*x5;  q.w -= t5*x4 + t6*x5 + t7*x6; }
#define ROLE_E(q) { \
    q.x += t5*x0 + t6*x2 + t7*x4;  q.y += t5*x1 + t6*x3 + t7*x5; \
    q.z += t5*x2 + t6*x4 + t7*x6;  q.w += t5*x3 + t6*x5 + t7*x7; \
    *(float4*)po = q;  po += WW; }

// full-role step: arriving row rr inits A-slot, updates B/C/D, finishes E
#define FULL(qA, qB, qC, qD, qE) { \
    EXT_SHIFT(1) \
    ROLE_A(qA) ROLE_B(qB) ROLE_C(qC) ROLE_D(qD) ROLE_E(qE) }

// one period of the slot rotation (5 rows), pattern for rr % 5 == 2,3,4,0,1
#define CYCLE5() \
    FULL(q4, q3, q2, q1, q0) \
    FULL(q0, q4, q3, q2, q1) \
    FULL(q1, q0, q4, q3, q2) \
    FULL(q2, q1, q0, q4, q3) \
    FULL(q3, q2, q1, q0, q4)

__global__ __launch_bounds__(256, 8) void rpdc_kernel(
    const float* __restrict__ x, const float* __restrict__ wt,
    float* __restrict__ out, int C)
{
    const int tid   = threadIdx.x;
    const int l     = tid & 31;                      // col-group lane (4 cols)
    const int s     = blockIdx.x * SPB + (tid >> 5); // strip = (plane, chunk)
    const int plane = s >> 2;                        // n*C + c
    const int h0    = (s & 3) * CHUNK;
    const int c     = plane & (C - 1);               // C = 256 (pow2)

    // taps: wave-uniform (even s, s+1 share plane) -> SGPRs via readfirstlane
    const float* wp = wt + (size_t)c * 9;
    const float t0 = rfl(wp[1]), t1 = rfl(wp[2]), t2 = rfl(wp[3]), t3 = rfl(wp[4]);
    const float t4 = rfl(wp[5]), t5 = rfl(wp[6]), t6 = rfl(wp[7]), t7 = rfl(wp[8]);

    const int w0 = l * 4;                            // first owned column
    const float ml = (l == 0) ? 0.f : 1.f;           // zero-pad masks
    const float mr = (l == 31) ? 0.f : 1.f;
    const int lane = tid & 63;
    const int upA  = ((lane - 1) & 63) * 4;          // bpermute byte addrs
    const int dnA  = ((lane + 1) & 63) * 4;

    const float* pn = x + (size_t)plane * (HH * WW) + (ptrdiff_t)(h0 - 2) * WW + w0;
    int rn = h0 - 2;                                 // absolute row of pn
    float* po = out + (size_t)plane * (HH * WW) + (size_t)h0 * WW + w0;

    float4 q0, q1, q2, q3, q4;                       // partial out rows (mod 5)
    float4 s0, s1;                                   // staged input rows
    float x0, x1, x2, x3, x4, x5, x6, x7;            // extended current row

    LOADROW(s0)                                      // row rr = -2
    LOADROW(s1)                                      // row rr = -1

    // prologue: rr = -2..1 (partial roles)
    EXT_SHIFT(1) ROLE_A(q0)                                    // rr=-2
    EXT_SHIFT(1) ROLE_A(q1) ROLE_B(q0)                         // rr=-1
    EXT_SHIFT(1) ROLE_A(q2) ROLE_B(q1) ROLE_C(q0)              // rr= 0
    EXT_SHIFT(1) ROLE_A(q3) ROLE_B(q2) ROLE_C(q1) ROLE_D(q0)   // rr= 1

    // main: rr = 2..26 (5 full rotation periods)
    CYCLE5() CYCLE5() CYCLE5() CYCLE5() CYCLE5()
    // rr = 27, 28, 29
    FULL(q4, q3, q2, q1, q0)
    FULL(q0, q4, q3, q2, q1)
    FULL(q1, q0, q4, q3, q2)

    // epilogue: rr = 30..33 (loads for rows 32,33 only; then drain)
    EXT_SHIFT(1) ROLE_B(q1) ROLE_C(q0) ROLE_D(q4) ROLE_E(q3)   // rr=30
    EXT_SHIFT(1) ROLE_C(q1) ROLE_D(q0) ROLE_E(q4)              // rr=31
    EXT_SHIFT(0) ROLE_D(q1) ROLE_E(q0)                         // rr=32
    EXT_SHIFT(0) ROLE_E(q1)                                    // rr=33
}

extern "C" void kernel_launch(void* const* d_in, const int* in_sizes, int n_in,
                              void* d_out, int out_size, void* d_ws, size_t ws_size,
                              hipStream_t stream) {
    const float* x = (const float*)d_in[0];
    const float* wt = (const float*)d_in[1];
    float* out = (float*)d_out;

    const int C = in_sizes[1] / 9;                 // 256
    const int planes = in_sizes[0] / (HH * WW);    // N*C = 4096

    // strips = planes * (HH/CHUNK); 8 strips (2 planes) per 256-thread block
    dim3 grid(planes * (HH / CHUNK) / SPB);        // 2048
    dim3 block(256);
    rpdc_kernel<<<grid, block, 0, stream>>>(x, wt, out, C);
}